// Round 7
// baseline (65098.022 us; speedup 1.0000x reference)
//
#include <hip/hip_runtime.h>
#include <cstdint>
#include <cstddef>

#define DEVI __device__ __forceinline__

DEVI float sigmoidf_(float x) { return 1.0f / (1.0f + __expf(-x)); }
DEVI float tanhf_(float x) { return 2.0f / (1.0f + __expf(-2.0f * x)) - 1.0f; }

// ---------------- diagnostic fill ------------------------------------------
__global__ void fill_const(float* __restrict__ p, int n, float v) {
    int i = blockIdx.x * 256 + threadIdx.x;
    if (i < n) p[i] = v;
}

// ---------------- f32 GEMM: C = epi(A @ B^T + bias) ------------------------
// A [M,K] row-major (lda), B [N,K] row-major (ldb). 64x64 tile, K-tile 32,
// 256 threads (16x16), 4x4 outputs per thread. Pure VALU.
// EPI 0: relu.  EPI 1: v -> eps*exp(0.5*v)+v (reparameterize, logvar==mu).
template <int EPI>
__global__ __launch_bounds__(256) void gemm_f32(
    const float* __restrict__ A, int lda, const float* __restrict__ B, int ldb,
    const float* __restrict__ bias, float* __restrict__ C, int ldc, int K,
    const float* __restrict__ eps) {
    __shared__ float As[64][33];
    __shared__ float Bs[64][33];
    const int tid = threadIdx.x;
    const int m0 = blockIdx.y * 64, n0 = blockIdx.x * 64;
    const int tx = tid & 15, ty = tid >> 4;
    const int sr = tid >> 2;        // staging row 0..63
    const int c8 = (tid & 3) * 8;   // staging col 0,8,16,24

    float acc[4][4] = {};

    for (int k0 = 0; k0 < K; k0 += 32) {
#pragma unroll
        for (int j = 0; j < 8; ++j) {
            int k = k0 + c8 + j;
            As[sr][c8 + j] = (k < K) ? A[(size_t)(m0 + sr) * lda + k] : 0.f;
            Bs[sr][c8 + j] = (k < K) ? B[(size_t)(n0 + sr) * ldb + k] : 0.f;
        }
        __syncthreads();
#pragma unroll 8
        for (int kk = 0; kk < 32; ++kk) {
            float a_[4], b_[4];
#pragma unroll
            for (int i = 0; i < 4; i++) a_[i] = As[ty * 4 + i][kk];
#pragma unroll
            for (int j = 0; j < 4; j++) b_[j] = Bs[tx * 4 + j][kk];
#pragma unroll
            for (int i = 0; i < 4; i++)
#pragma unroll
                for (int j = 0; j < 4; j++) acc[i][j] += a_[i] * b_[j];
        }
        __syncthreads();
    }
#pragma unroll
    for (int i = 0; i < 4; i++) {
        int row = m0 + ty * 4 + i;
#pragma unroll
        for (int j = 0; j < 4; j++) {
            int col = n0 + tx * 4 + j;
            float v = acc[i][j] + bias[col];
            if (EPI == 0) {
                v = v > 0.f ? v : 0.f;
            } else {
                float e = eps[(size_t)row * 512 + col];
                v = e * __expf(0.5f * v) + v;
            }
            C[(size_t)row * ldc + col] = v;
        }
    }
}

// ---------------- weight transpose: W [1536,512] -> WT [512,1536] ----------
__global__ __launch_bounds__(512) void transpose_w(const float* __restrict__ W,
                                                   float* __restrict__ WT) {
    int g = blockIdx.x;      // 0..1535
    int k = threadIdx.x;     // 0..511
    WT[(size_t)k * 1536 + g] = W[(size_t)g * 512 + k];
}

// ---------------- GRU gates + state update (pure f32) ----------------------
__global__ __launch_bounds__(512) void gru_gates_f32(
    const float* __restrict__ xt, const float* __restrict__ h,
    const float* __restrict__ WTih, const float* __restrict__ WThh,
    const float* __restrict__ bih, const float* __restrict__ bhh,
    float* __restrict__ h_out) {
    __shared__ float xs[512], hs[512];
    const int row = blockIdx.x;
    const int u = threadIdx.x;
    xs[u] = xt[(size_t)row * 512 + u];
    hs[u] = h[(size_t)row * 512 + u];
    __syncthreads();
    float gr = bih[u] + bhh[u];
    float gz = bih[512 + u] + bhh[512 + u];
    float gin = bih[1024 + u];
    float ghn = bhh[1024 + u];
    for (int k = 0; k < 512; ++k) {
        float xv = xs[k], hv = hs[k];
        const float* wi = WTih + (size_t)k * 1536;
        const float* wh = WThh + (size_t)k * 1536;
        gr += xv * wi[u] + hv * wh[u];
        gz += xv * wi[512 + u] + hv * wh[512 + u];
        gin += xv * wi[1024 + u];
        ghn += hv * wh[1024 + u];
    }
    float rv = sigmoidf_(gr);
    float zv = sigmoidf_(gz);
    float nv = tanhf_(gin + rv * ghn);
    h_out[(size_t)row * 512 + u] = (1.f - zv) * nv + zv * hs[u];
}

// ---------------- fc1 + fc2 (f32): out_{s-1} and x_s from h_s --------------
// 256 blocks x 384 threads, 8 batch rows per block.
// FIX (R7): fc1 needs 8 rows x 42 outs = 336 threads; previous rounds
// launched 256 => batch rows b%8==7 were NEVER written (the 0.37890625 bug).
__global__ __launch_bounds__(384) void gru_fc_f32(
    const float* __restrict__ hf, const float* __restrict__ Wf1,
    const float* __restrict__ bf1, const float* __restrict__ Wf2,
    const float* __restrict__ bf2, float* __restrict__ outp,
    float* __restrict__ xt_out) {
    __shared__ float hs[8 * 512];
    __shared__ float outs[8 * 48];
    const int tid = threadIdx.x;
    const int r0 = blockIdx.x * 8;
    const float4* hg = (const float4*)(hf + (size_t)r0 * 512);
    float4* hl = (float4*)hs;
    for (int i = tid; i < 1024; i += 384) hl[i] = hg[i];
    __syncthreads();
    if (tid < 336) {
        int row = tid / 42, o = tid % 42;
        const float4* hp = (const float4*)&hs[row * 512];
        const float4* wp = (const float4*)&Wf1[(size_t)o * 512];
        float s = bf1[o];
#pragma unroll 4
        for (int k = 0; k < 128; k++) {
            float4 h4 = hp[k], w4 = wp[k];
            s += h4.x * w4.x + h4.y * w4.y + h4.z * w4.z + h4.w * w4.w;
        }
        s = s > 0.f ? s : 0.f;
        outs[row * 48 + o] = s;
        outp[(size_t)(r0 + row) * 5376 + o] = s;  // d_out[b][step][o]
    }
    __syncthreads();
    if (tid < 256) {
        int row = tid >> 5, c0 = (tid & 31) * 16;
#pragma unroll 4
        for (int cc = 0; cc < 16; ++cc) {
            int col = c0 + cc;
            const float* wp = &Wf2[(size_t)col * 42];
            float s = bf2[col];
#pragma unroll 6
            for (int o = 0; o < 42; o++) s += outs[row * 48 + o] * wp[o];
            s = s > 0.f ? s : 0.f;
            xt_out[(size_t)(r0 + row) * 512 + col] = s;
        }
    }
}

// ---------------------------------------------------------------------------
extern "C" void kernel_launch(void* const* d_in, const int* in_sizes, int n_in,
                              void* d_out, int out_size, void* d_ws,
                              size_t ws_size, hipStream_t stream) {
    (void)in_sizes; (void)n_in; (void)out_size;
    // Insertion (setup_inputs dict) order — size-probe confirmed in R4.
    const float* x = (const float*)d_in[0];
    const float* eps = (const float*)d_in[2];
    const float* We1 = (const float*)d_in[3];
    const float* be1 = (const float*)d_in[4];
    const float* We2 = (const float*)d_in[5];
    const float* be2 = (const float*)d_in[6];
    const float* We3 = (const float*)d_in[7];
    const float* be3 = (const float*)d_in[8];
    const float* We41 = (const float*)d_in[9];
    const float* be41 = (const float*)d_in[10];
    const float* Wih = (const float*)d_in[11];
    const float* bih = (const float*)d_in[12];
    const float* Whh = (const float*)d_in[13];
    const float* bhh = (const float*)d_in[14];
    const float* Wf1 = (const float*)d_in[15];
    const float* bf1 = (const float*)d_in[16];
    const float* Wf2 = (const float*)d_in[17];
    const float* bf2 = (const float*)d_in[18];
    float* out = (float*)d_out;

    char* ws = (char*)d_ws;
    size_t off = 0;
    auto alloc = [&](size_t bytes) -> char* {
        char* p = ws + off;
        off += (bytes + 255) & ~(size_t)255;
        return p;
    };
    float* h1 = (float*)alloc(2048ull * 2048 * 4);
    float* h2 = (float*)alloc(2048ull * 1024 * 4);
    float* h3 = (float*)alloc(2048ull * 512 * 4);
    float* enc = (float*)alloc(2048ull * 512 * 4);
    float* WTih = (float*)alloc(512ull * 1536 * 4);
    float* WThh = (float*)alloc(512ull * 1536 * 4);
    float* xtf = (float*)alloc(2048ull * 512 * 4);
    float* hf0 = (float*)alloc(2048ull * 512 * 4);
    float* hf1 = (float*)alloc(2048ull * 512 * 4);
    if (off > ws_size) {
        fill_const<<<(11010048 + 255) / 256, 256, 0, stream>>>(out, 11010048, 54321.0f);
        return;
    }
    float* hf[2] = {hf0, hf1};

    // weight transposes for coalesced gate reads
    transpose_w<<<1536, 512, 0, stream>>>(Wih, WTih);
    transpose_w<<<1536, 512, 0, stream>>>(Whh, WThh);
    hipMemsetAsync(hf[0], 0, 2048ull * 512 * 4, stream);

    // encoder (pure f32)
    gemm_f32<0><<<dim3(32, 32), 256, 0, stream>>>(x, 4860, We1, 4860, be1, h1, 2048, 4860, nullptr);
    gemm_f32<0><<<dim3(16, 32), 256, 0, stream>>>(h1, 2048, We2, 2048, be2, h2, 1024, 2048, nullptr);
    gemm_f32<0><<<dim3(8, 32), 256, 0, stream>>>(h2, 1024, We3, 1024, be3, h3, 512, 1024, nullptr);
    gemm_f32<1><<<dim3(8, 32), 256, 0, stream>>>(h3, 512, We41, 512, be41, enc, 512, 512, eps);

    // decoder: h_{s+1} = gates(x_s, h_s); out_{s-1}, x_s = fc(h_s)
    gru_gates_f32<<<2048, 512, 0, stream>>>(enc, hf[0], WTih, WThh, bih, bhh, hf[1]);
    for (int s = 1; s < 128; ++s) {
        int p = s & 1;
        gru_fc_f32<<<256, 384, 0, stream>>>(hf[p], Wf1, bf1, Wf2, bf2,
                                            out + (size_t)(s - 1) * 42, xtf);
        gru_gates_f32<<<2048, 512, 0, stream>>>(xtf, hf[p], WTih, WThh, bih, bhh,
                                                hf[p ^ 1]);
    }
    gru_fc_f32<<<256, 384, 0, stream>>>(hf[0], Wf1, bf1, Wf2, bf2,
                                        out + 127ull * 42, xtf);
}

// Round 8
// 10637.836 us; speedup vs baseline: 6.1195x; 6.1195x over previous
//
#include <hip/hip_runtime.h>
#include <hip/hip_bf16.h>
#include <cstdint>
#include <cstddef>

#define DEVI __device__ __forceinline__

typedef __attribute__((ext_vector_type(8))) short bf16x8;
typedef __attribute__((ext_vector_type(4))) float f32x4;
typedef unsigned short u16;
typedef unsigned int u32;

DEVI u16 f2bf(float f) {
    u32 i = __builtin_bit_cast(u32, f);
    u32 r = (i + 0x7FFFu + ((i >> 16) & 1u)) >> 16;
    return (u16)r;
}
DEVI float sigmoidf_(float x) { return 1.0f / (1.0f + __expf(-x)); }
DEVI float tanhf_(float x) { return 2.0f / (1.0f + __expf(-2.0f * x)) - 1.0f; }

typedef const __attribute__((address_space(1))) void* gptr_t;
typedef __attribute__((address_space(3))) void* lptr_t;

DEVI void gload16(const void* g, void* l) {
    __builtin_amdgcn_global_load_lds((gptr_t)g, (lptr_t)l, 16, 0, 0);
}

__global__ void fill_const(float* __restrict__ p, int n, float v) {
    int i = blockIdx.x * 256 + threadIdx.x;
    if (i < n) p[i] = v;
}

// ---------------- f32 -> bf16 convert (with optional zero K-padding) -------
__global__ void cvt_pad(const float* __restrict__ src, u16* __restrict__ dst,
                        int wcols, int cols, int spitch, int dpitch) {
    int c = blockIdx.x * 256 + threadIdx.x;
    int r = blockIdx.y;
    if (c >= wcols) return;
    float v = (c < cols) ? src[(size_t)r * spitch + c] : 0.0f;
    dst[(size_t)r * dpitch + c] = f2bf(v);
}

// ---------------- encoder GEMM: C = epi(A @ B^T + bias) --------------------
// A [M,K] bf16 (lda), B [N,K] bf16 (ldb), 128x128 tile, BK=64, 4 waves 2x2,
// each wave 64x64 (4x4 frags of 16x16x32). EPI0: relu->bf16. EPI1: reparam.
template <int EPI>
__global__ __launch_bounds__(256) void gemm_bt(
    const u16* __restrict__ A, int lda, const u16* __restrict__ B, int ldb,
    const float* __restrict__ bias, u16* __restrict__ C, int ldc, int ktiles,
    const float* __restrict__ eps) {
    __shared__ u16 As[128 * 64];
    __shared__ u16 Bs[128 * 64];
    const int tid = threadIdx.x;
    const int lane = tid & 63;
    const int wave = tid >> 6;
    const int m0 = blockIdx.y * 128;
    const int n0 = blockIdx.x * 128;
    const int l15 = lane & 15, lg = lane >> 4;
    const int wm = (wave >> 1) * 64, wn = (wave & 1) * 64;

    f32x4 acc[4][4];
#pragma unroll
    for (int r = 0; r < 4; r++)
#pragma unroll
        for (int c = 0; c < 4; c++) acc[r][c] = (f32x4){0.f, 0.f, 0.f, 0.f};

    for (int t = 0; t < ktiles; ++t) {
        const int k0 = t * 64;
#pragma unroll
        for (int q = 0; q < 4; ++q) {
            int chunk = q * 4 + wave;
            int o = chunk * 1024 + lane * 16;  // byte offset inside 16KB tile
            int row = o >> 7;
            int cb = o & 127;
            gload16((const char*)(A + (size_t)(m0 + row) * lda + k0) + cb,
                    (char*)As + chunk * 1024);
            gload16((const char*)(B + (size_t)(n0 + row) * ldb + k0) + cb,
                    (char*)Bs + chunk * 1024);
        }
        __syncthreads();
#pragma unroll
        for (int kf = 0; kf < 2; ++kf) {
            bf16x8 a[4], b[4];
#pragma unroll
            for (int r = 0; r < 4; r++)
                a[r] = *(const bf16x8*)&As[(wm + 16 * r + l15) * 64 + kf * 32 + lg * 8];
#pragma unroll
            for (int c = 0; c < 4; c++)
                b[c] = *(const bf16x8*)&Bs[(wn + 16 * c + l15) * 64 + kf * 32 + lg * 8];
#pragma unroll
            for (int r = 0; r < 4; r++)
#pragma unroll
                for (int c = 0; c < 4; c++)
                    acc[r][c] = __builtin_amdgcn_mfma_f32_16x16x32_bf16(
                        a[r], b[c], acc[r][c], 0, 0, 0);
        }
        __syncthreads();
    }
#pragma unroll
    for (int r = 0; r < 4; r++) {
#pragma unroll
        for (int c = 0; c < 4; c++) {
            int col = n0 + wn + 16 * c + l15;
            float bv = bias[col];
#pragma unroll
            for (int i = 0; i < 4; i++) {
                int row = m0 + wm + 16 * r + lg * 4 + i;
                float v = acc[r][c][i] + bv;
                if (EPI == 0) {
                    v = v > 0.f ? v : 0.f;
                    C[(size_t)row * ldc + col] = f2bf(v);
                } else {
                    float e = eps[(size_t)row * 512 + col];
                    float enc = e * __expf(0.5f * v) + v;
                    C[(size_t)row * ldc + col] = f2bf(enc);
                }
            }
        }
    }
}

// ---------------- GRU gates + state update (bf16 MFMA) ---------------------
// Grid (8 hidden-tiles, 32 row-tiles), 256 threads. 64 rows x 64 units per
// WG: r,z concat-K over [xt||h] (K=1024); gi_n/gh_n split at k=512.
// WB [1536,1024] bf16: WB[g][0:512]=Wih[g], WB[g][512:1024]=Whh[g].
__global__ __launch_bounds__(256) void gru_gates(
    const u16* __restrict__ xt, const u16* __restrict__ hb,
    const float* __restrict__ hf, const u16* __restrict__ WB,
    const float* __restrict__ bih, const float* __restrict__ bhh,
    u16* __restrict__ hb_out, float* __restrict__ hf_out) {
    __shared__ u16 As[64 * 64];   // 8KB
    __shared__ u16 Bs[192 * 64];  // 24KB (r | z | n)
    const int tid = threadIdx.x, lane = tid & 63, wave = tid >> 6;
    const int S = blockIdx.x * 64;
    const int m0 = blockIdx.y * 64;
    const int l15 = lane & 15, lg = lane >> 4;

    f32x4 accr[4], accz[4], accgi[4], accgh[4];
#pragma unroll
    for (int c = 0; c < 4; c++) {
        accr[c] = (f32x4){0.f, 0.f, 0.f, 0.f};
        accz[c] = (f32x4){0.f, 0.f, 0.f, 0.f};
        accgi[c] = (f32x4){0.f, 0.f, 0.f, 0.f};
        accgh[c] = (f32x4){0.f, 0.f, 0.f, 0.f};
    }

    for (int t = 0; t < 16; ++t) {
        const u16* src = (t < 8) ? xt : hb;
        const int kc = (t & 7) * 64;
#pragma unroll
        for (int q = 0; q < 2; ++q) {  // A: 8 chunks of 1KB
            int chunk = q * 4 + wave;
            int o = chunk * 1024 + lane * 16;
            int row = o >> 7, cb = o & 127;
            gload16((const char*)(src + (size_t)(m0 + row) * 512 + kc) + cb,
                    (char*)As + chunk * 1024);
        }
#pragma unroll
        for (int q = 0; q < 6; ++q) {  // B: 24 chunks of 1KB
            int chunk = q * 4 + wave;
            int o = chunk * 1024 + lane * 16;
            int lr = o >> 7, cb = o & 127;
            int j = lr >> 6, rr = lr & 63;
            gload16((const char*)(WB + (size_t)(j * 512 + S + rr) * 1024 + t * 64) + cb,
                    (char*)Bs + chunk * 1024);
        }
        __syncthreads();
#pragma unroll
        for (int kf = 0; kf < 2; ++kf) {
            bf16x8 a = *(const bf16x8*)&As[(wave * 16 + l15) * 64 + kf * 32 + lg * 8];
            bf16x8 br[4], bz[4], bn[4];
#pragma unroll
            for (int c = 0; c < 4; c++) {
                br[c] = *(const bf16x8*)&Bs[(16 * c + l15) * 64 + kf * 32 + lg * 8];
                bz[c] = *(const bf16x8*)&Bs[(64 + 16 * c + l15) * 64 + kf * 32 + lg * 8];
                bn[c] = *(const bf16x8*)&Bs[(128 + 16 * c + l15) * 64 + kf * 32 + lg * 8];
            }
#pragma unroll
            for (int c = 0; c < 4; c++) {
                accr[c] = __builtin_amdgcn_mfma_f32_16x16x32_bf16(a, br[c], accr[c], 0, 0, 0);
                accz[c] = __builtin_amdgcn_mfma_f32_16x16x32_bf16(a, bz[c], accz[c], 0, 0, 0);
            }
            if (t < 8) {
#pragma unroll
                for (int c = 0; c < 4; c++)
                    accgi[c] = __builtin_amdgcn_mfma_f32_16x16x32_bf16(a, bn[c], accgi[c], 0, 0, 0);
            } else {
#pragma unroll
                for (int c = 0; c < 4; c++)
                    accgh[c] = __builtin_amdgcn_mfma_f32_16x16x32_bf16(a, bn[c], accgh[c], 0, 0, 0);
            }
        }
        __syncthreads();
    }
#pragma unroll
    for (int c = 0; c < 4; c++) {
        int hu = S + 16 * c + l15;
        float br_ = bih[hu] + bhh[hu];
        float bz_ = bih[512 + hu] + bhh[512 + hu];
        float bgi = bih[1024 + hu];
        float bgh = bhh[1024 + hu];
#pragma unroll
        for (int i = 0; i < 4; i++) {
            int row = m0 + wave * 16 + lg * 4 + i;
            float rv = sigmoidf_(accr[c][i] + br_);
            float zv = sigmoidf_(accz[c][i] + bz_);
            float nv = tanhf_(accgi[c][i] + bgi + rv * (accgh[c][i] + bgh));
            float hold = hf[(size_t)row * 512 + hu];
            float hn = (1.f - zv) * nv + zv * hold;
            hf_out[(size_t)row * 512 + hu] = hn;
            hb_out[(size_t)row * 512 + hu] = f2bf(hn);
        }
    }
}

// ---------------- fc1 + fc2 (f32): out_{s-1} and x_s from h_s --------------
// 256 blocks x 384 threads, 8 batch rows per block.
// fc1 needs 8*42=336 threads (the historic 256-thread bug is FIXED here).
__global__ __launch_bounds__(384) void gru_fc(
    const float* __restrict__ hf, const float* __restrict__ Wf1,
    const float* __restrict__ bf1, const float* __restrict__ Wf2,
    const float* __restrict__ bf2, float* __restrict__ outp,
    u16* __restrict__ xt_out) {
    __shared__ float hs[8 * 512];
    __shared__ float outs[8 * 48];
    const int tid = threadIdx.x;
    const int r0 = blockIdx.x * 8;
    const float4* hg = (const float4*)(hf + (size_t)r0 * 512);
    float4* hl = (float4*)hs;
    for (int i = tid; i < 1024; i += 384) hl[i] = hg[i];
    __syncthreads();
    if (tid < 336) {
        int row = tid / 42, o = tid % 42;
        const float4* hp = (const float4*)&hs[row * 512];
        const float4* wp = (const float4*)&Wf1[(size_t)o * 512];
        float s = bf1[o];
#pragma unroll 4
        for (int k = 0; k < 128; k++) {
            float4 h4 = hp[k], w4 = wp[k];
            s += h4.x * w4.x + h4.y * w4.y + h4.z * w4.z + h4.w * w4.w;
        }
        s = s > 0.f ? s : 0.f;
        outs[row * 48 + o] = s;
        outp[(size_t)(r0 + row) * 5376 + o] = s;  // d_out[b][step][o]
    }
    __syncthreads();
    if (tid < 256) {
        int row = tid >> 5, c0 = (tid & 31) * 16;
#pragma unroll 4
        for (int cc = 0; cc < 16; ++cc) {
            int col = c0 + cc;
            const float* wp = &Wf2[(size_t)col * 42];
            float s = bf2[col];
#pragma unroll 6
            for (int o = 0; o < 42; o++) s += outs[row * 48 + o] * wp[o];
            s = s > 0.f ? s : 0.f;
            xt_out[(size_t)(r0 + row) * 512 + col] = f2bf(s);
        }
    }
}

// ---------------------------------------------------------------------------
extern "C" void kernel_launch(void* const* d_in, const int* in_sizes, int n_in,
                              void* d_out, int out_size, void* d_ws,
                              size_t ws_size, hipStream_t stream) {
    (void)in_sizes; (void)n_in; (void)out_size;
    const float* x = (const float*)d_in[0];
    const float* eps = (const float*)d_in[2];
    const float* We1 = (const float*)d_in[3];
    const float* be1 = (const float*)d_in[4];
    const float* We2 = (const float*)d_in[5];
    const float* be2 = (const float*)d_in[6];
    const float* We3 = (const float*)d_in[7];
    const float* be3 = (const float*)d_in[8];
    const float* We41 = (const float*)d_in[9];
    const float* be41 = (const float*)d_in[10];
    const float* Wih = (const float*)d_in[11];
    const float* bih = (const float*)d_in[12];
    const float* Whh = (const float*)d_in[13];
    const float* bhh = (const float*)d_in[14];
    const float* Wf1 = (const float*)d_in[15];
    const float* bf1 = (const float*)d_in[16];
    const float* Wf2 = (const float*)d_in[17];
    const float* bf2 = (const float*)d_in[18];
    float* out = (float*)d_out;

    char* ws = (char*)d_ws;
    size_t off = 0;
    auto alloc = [&](size_t bytes) -> char* {
        char* p = ws + off;
        off += (bytes + 255) & ~(size_t)255;
        return p;
    };
    u16* xb = (u16*)alloc(2048ull * 4864 * 2);
    u16* We1b = (u16*)alloc(2048ull * 4864 * 2);
    u16* We2b = (u16*)alloc(1024ull * 2048 * 2);
    u16* We3b = (u16*)alloc(512ull * 1024 * 2);
    u16* We41b = (u16*)alloc(512ull * 512 * 2);
    u16* WB = (u16*)alloc(1536ull * 1024 * 2);
    u16* h1b = (u16*)alloc(2048ull * 2048 * 2);
    u16* h2b = (u16*)alloc(2048ull * 1024 * 2);
    u16* h3b = (u16*)alloc(2048ull * 512 * 2);
    u16* encb = (u16*)alloc(2048ull * 512 * 2);
    u16* xtb = (u16*)alloc(2048ull * 512 * 2);
    u16* hb0 = (u16*)alloc(2048ull * 512 * 2);
    u16* hb1 = (u16*)alloc(2048ull * 512 * 2);
    float* hf0 = (float*)alloc(2048ull * 512 * 4);
    float* hf1 = (float*)alloc(2048ull * 512 * 4);
    if (off > ws_size) {
        fill_const<<<(11010048 + 255) / 256, 256, 0, stream>>>(out, 11010048, 54321.0f);
        return;
    }
    u16* hb[2] = {hb0, hb1};
    float* hfl[2] = {hf0, hf1};

    auto cdiv = [](int a, int b) { return (a + b - 1) / b; };
    // weight / input conversions to bf16 (zero-pad K 4860 -> 4864)
    cvt_pad<<<dim3(cdiv(4864, 256), 2048), 256, 0, stream>>>(x, xb, 4864, 4860, 4860, 4864);
    cvt_pad<<<dim3(cdiv(4864, 256), 2048), 256, 0, stream>>>(We1, We1b, 4864, 4860, 4860, 4864);
    cvt_pad<<<dim3(cdiv(2048, 256), 1024), 256, 0, stream>>>(We2, We2b, 2048, 2048, 2048, 2048);
    cvt_pad<<<dim3(cdiv(1024, 256), 512), 256, 0, stream>>>(We3, We3b, 1024, 1024, 1024, 1024);
    cvt_pad<<<dim3(cdiv(512, 256), 512), 256, 0, stream>>>(We41, We41b, 512, 512, 512, 512);
    cvt_pad<<<dim3(cdiv(512, 256), 1536), 256, 0, stream>>>(Wih, WB, 512, 512, 512, 1024);
    cvt_pad<<<dim3(cdiv(512, 256), 1536), 256, 0, stream>>>(Whh, WB + 512, 512, 512, 512, 1024);
    hipMemsetAsync(hb[0], 0, 2048ull * 512 * 2, stream);
    hipMemsetAsync(hfl[0], 0, 2048ull * 512 * 4, stream);

    // encoder (bf16 MFMA)
    gemm_bt<0><<<dim3(16, 16), 256, 0, stream>>>(xb, 4864, We1b, 4864, be1, h1b, 2048, 76, nullptr);
    gemm_bt<0><<<dim3(8, 16), 256, 0, stream>>>(h1b, 2048, We2b, 2048, be2, h2b, 1024, 32, nullptr);
    gemm_bt<0><<<dim3(4, 16), 256, 0, stream>>>(h2b, 1024, We3b, 1024, be3, h3b, 512, 16, nullptr);
    gemm_bt<1><<<dim3(4, 16), 256, 0, stream>>>(h3b, 512, We41b, 512, be41, encb, 512, 8, eps);

    // decoder: h_{s+1} = gates(x_s, h_s); out_{s-1}, x_s = fc(h_s)
    gru_gates<<<dim3(8, 32), 256, 0, stream>>>(encb, hb[0], hfl[0], WB, bih, bhh, hb[1], hfl[1]);
    for (int s = 1; s < 128; ++s) {
        int p = s & 1;
        gru_fc<<<256, 384, 0, stream>>>(hfl[p], Wf1, bf1, Wf2, bf2,
                                        out + (size_t)(s - 1) * 42, xtb);
        gru_gates<<<dim3(8, 32), 256, 0, stream>>>(xtb, hb[p], hfl[p], WB, bih, bhh,
                                                   hb[p ^ 1], hfl[p ^ 1]);
    }
    gru_fc<<<256, 384, 0, stream>>>(hfl[0], Wf1, bf1, Wf2, bf2,
                                    out + 127ull * 42, xtb);
}

// Round 10
// 5103.381 us; speedup vs baseline: 12.7559x; 2.0845x over previous
//
#include <hip/hip_runtime.h>
#include <hip/hip_bf16.h>
#include <cstdint>
#include <cstddef>

#define DEVI __device__ __forceinline__

typedef __attribute__((ext_vector_type(8))) short bf16x8;
typedef __attribute__((ext_vector_type(4))) float f32x4;
typedef unsigned short u16;
typedef unsigned int u32;
typedef unsigned long long u64;

DEVI u16 f2bf(float f) {
    u32 i = __builtin_bit_cast(u32, f);
    u32 r = (i + 0x7FFFu + ((i >> 16) & 1u)) >> 16;
    return (u16)r;
}
DEVI float sigmoidf_(float x) { return 1.0f / (1.0f + __expf(-x)); }
DEVI float tanhf_(float x) { return 2.0f / (1.0f + __expf(-2.0f * x)) - 1.0f; }

typedef const __attribute__((address_space(1))) void* gptr_t;
typedef __attribute__((address_space(3))) void* lptr_t;

DEVI void gload16(const void* g, void* l) {
    __builtin_amdgcn_global_load_lds((gptr_t)g, (lptr_t)l, 16, 0, 0);
}

__global__ void fill_const(float* __restrict__ p, int n, float v) {
    int i = blockIdx.x * 256 + threadIdx.x;
    if (i < n) p[i] = v;
}

// ---------------- f32 -> bf16 convert (with optional zero K-padding) -------
__global__ void cvt_pad(const float* __restrict__ src, u16* __restrict__ dst,
                        int wcols, int cols, int spitch, int dpitch) {
    int c = blockIdx.x * 256 + threadIdx.x;
    int r = blockIdx.y;
    if (c >= wcols) return;
    float v = (c < cols) ? src[(size_t)r * spitch + c] : 0.0f;
    dst[(size_t)r * dpitch + c] = f2bf(v);
}

// ---------------- fc weight prep (bf16, zero-padded) -----------------------
__global__ void prep_wf1(const float* __restrict__ Wf1, u16* __restrict__ Wf1p) {
    int r = blockIdx.x;   // 0..47
    int c = threadIdx.x;  // 0..511
    Wf1p[r * 512 + c] = (r < 42) ? f2bf(Wf1[(size_t)r * 512 + c]) : (u16)0;
}
__global__ void prep_wf2(const float* __restrict__ Wf2, u16* __restrict__ Wf2p) {
    int c = blockIdx.x;   // 0..511
    int k = threadIdx.x;  // 0..63
    Wf2p[c * 64 + k] = (k < 42) ? f2bf(Wf2[(size_t)c * 42 + k]) : (u16)0;
}

// ---------------- encoder GEMM: C = epi(A @ B^T + bias) (R8-validated) -----
template <int EPI>
__global__ __launch_bounds__(256) void gemm_bt(
    const u16* __restrict__ A, int lda, const u16* __restrict__ B, int ldb,
    const float* __restrict__ bias, u16* __restrict__ C, int ldc, int ktiles,
    const float* __restrict__ eps) {
    __shared__ u16 As[128 * 64];
    __shared__ u16 Bs[128 * 64];
    const int tid = threadIdx.x;
    const int lane = tid & 63;
    const int wave = tid >> 6;
    const int m0 = blockIdx.y * 128;
    const int n0 = blockIdx.x * 128;
    const int l15 = lane & 15, lg = lane >> 4;
    const int wm = (wave >> 1) * 64, wn = (wave & 1) * 64;

    f32x4 acc[4][4];
#pragma unroll
    for (int r = 0; r < 4; r++)
#pragma unroll
        for (int c = 0; c < 4; c++) acc[r][c] = (f32x4){0.f, 0.f, 0.f, 0.f};

    for (int t = 0; t < ktiles; ++t) {
        const int k0 = t * 64;
#pragma unroll
        for (int q = 0; q < 4; ++q) {
            int chunk = q * 4 + wave;
            int o = chunk * 1024 + lane * 16;
            int row = o >> 7;
            int cb = o & 127;
            gload16((const char*)(A + (size_t)(m0 + row) * lda + k0) + cb,
                    (char*)As + chunk * 1024);
            gload16((const char*)(B + (size_t)(n0 + row) * ldb + k0) + cb,
                    (char*)Bs + chunk * 1024);
        }
        __syncthreads();
#pragma unroll
        for (int kf = 0; kf < 2; ++kf) {
            bf16x8 a[4], b[4];
#pragma unroll
            for (int r = 0; r < 4; r++)
                a[r] = *(const bf16x8*)&As[(wm + 16 * r + l15) * 64 + kf * 32 + lg * 8];
#pragma unroll
            for (int c = 0; c < 4; c++)
                b[c] = *(const bf16x8*)&Bs[(wn + 16 * c + l15) * 64 + kf * 32 + lg * 8];
#pragma unroll
            for (int r = 0; r < 4; r++)
#pragma unroll
                for (int c = 0; c < 4; c++)
                    acc[r][c] = __builtin_amdgcn_mfma_f32_16x16x32_bf16(
                        a[r], b[c], acc[r][c], 0, 0, 0);
        }
        __syncthreads();
    }
#pragma unroll
    for (int r = 0; r < 4; r++) {
#pragma unroll
        for (int c = 0; c < 4; c++) {
            int col = n0 + wn + 16 * c + l15;
            float bv = bias[col];
#pragma unroll
            for (int i = 0; i < 4; i++) {
                int row = m0 + wm + 16 * r + lg * 4 + i;
                float v = acc[r][c][i] + bv;
                if (EPI == 0) {
                    v = v > 0.f ? v : 0.f;
                    C[(size_t)row * ldc + col] = f2bf(v);
                } else {
                    float e = eps[(size_t)row * 512 + col];
                    float enc = e * __expf(0.5f * v) + v;
                    C[(size_t)row * ldc + col] = f2bf(enc);
                }
            }
        }
    }
}

// ================= FUSED PER-STEP DECODER KERNEL ===========================
// MODE 0: first step  — stage xt=encoded into LDS, gates only.
// MODE 1: middle step — fc1(h_i)->out[i-1]; fc2->xt_i (LDS only); gates->h_{i+1}.
// MODE 2: last        — fc1(h_128)->out[127] only.  Grid (1,32).
// Block (sb=blockIdx.x, rb=blockIdx.y): 64 batch rows (m0=rb*64), 64 hidden
// units (S=sb*64). fc computed redundantly per sb (cheap); out by sb==0.
// All inter-step dataflow via global buffers across launches (coherent).
// LDS tiles XOR-swizzled (T2): byte ^= ((row&7)<<4); gload16 sources
// pre-swizzled (G21: linear dest + inverse-swizzled source).
template <int MODE>
__global__ __launch_bounds__(256, 1) void gru_step(
    const u16* __restrict__ xt0, const u16* __restrict__ hbR,
    const float* __restrict__ hfR, u16* __restrict__ hbW,
    float* __restrict__ hfW, const u16* __restrict__ WB,
    const float* __restrict__ bih, const float* __restrict__ bhh,
    const u16* __restrict__ Wf1p, const float* __restrict__ bf1,
    const u16* __restrict__ Wf2p, const float* __restrict__ bf2,
    float* __restrict__ outp, int sidx) {
    __shared__ __align__(16) u16 xtL[64 * 512];  // 64KB swizzled xt tile
    __shared__ __align__(16) u16 Bst[192 * 64];  // 24KB swizzled gate-W tile
    __shared__ __align__(16) u16 oL[64 * 64];    // 8KB swizzled fc1-out tile
    const int tid = threadIdx.x, lane = tid & 63, wave = tid >> 6;
    const int S = blockIdx.x * 64, m0 = blockIdx.y * 64;
    const int l15 = lane & 15, lg = lane >> 4;

    if (MODE == 0) {
        // stage xtL from encoded (1KB row per issue; src seg pre-swizzled)
        for (int q = 0; q < 16; ++q) {
            int row = wave * 16 + q;
            const char* src = (const char*)(xt0 + (size_t)(m0 + row) * 512) +
                              ((lane ^ (row & 7)) * 16);
            gload16(src, (char*)xtL + row * 1024);
        }
        __syncthreads();
    }

    if (MODE >= 1) {
        // zero-fill oL pad cols 48..63 (32B block at swizzled position)
        {
            int row = tid >> 2, part = tid & 3;
            int base = ((6 ^ (row & 7)) & ~1) * 16;
            *(u64*)((char*)oL + row * 128 + base + part * 8) = 0ull;
        }
        // ---- fc1: o[64x48] = relu(h[64x512] @ Wf1p^T + bf1) ----
        f32x4 oa[3];
#pragma unroll
        for (int c = 0; c < 3; c++) oa[c] = (f32x4){0.f, 0.f, 0.f, 0.f};
        const u16* hsrc = hbR + (size_t)(m0 + 16 * wave + l15) * 512 + lg * 8;
        const u16* w1src = Wf1p + (size_t)l15 * 512 + lg * 8;
#pragma unroll
        for (int kf = 0; kf < 16; ++kf) {
            bf16x8 a = *(const bf16x8*)(hsrc + kf * 32);
#pragma unroll
            for (int c = 0; c < 3; ++c) {
                bf16x8 b = *(const bf16x8*)(w1src + c * 16 * 512 + kf * 32);
                oa[c] = __builtin_amdgcn_mfma_f32_16x16x32_bf16(a, b, oa[c], 0, 0, 0);
            }
        }
#pragma unroll
        for (int c = 0; c < 3; ++c) {
            int col = 16 * c + l15;
            float bv = (col < 42) ? bf1[col] : 0.f;
#pragma unroll
            for (int i = 0; i < 4; ++i) {
                int lrow = 16 * wave + lg * 4 + i;
                float v = oa[c][i] + bv;
                v = v > 0.f ? v : 0.f;
                if (col >= 42) v = 0.f;
                int cb = col * 2;
                int byo = lrow * 128 + (((cb & ~15) ^ ((lrow & 7) << 4)) | (cb & 15));
                *(u16*)((char*)oL + byo) = f2bf(v);
                if (blockIdx.x == 0 && col < 42)
                    outp[(size_t)(m0 + lrow) * 5376 + (size_t)sidx * 42 + col] = v;
            }
        }
        __syncthreads();
    }

    if (MODE == 1) {
        // ---- fc2: xt[64x512] = relu(o[64x64pad] @ Wf2p^T + bf2) -> xtL ----
        f32x4 xa[32];
#pragma unroll
        for (int ct = 0; ct < 32; ct++) xa[ct] = (f32x4){0.f, 0.f, 0.f, 0.f};
        bf16x8 a2[2];
#pragma unroll
        for (int kf = 0; kf < 2; ++kf) {
            int row = 16 * wave + l15;
            int byo = row * 128 + ((kf * 64 + lg * 16) ^ ((row & 7) << 4));
            a2[kf] = *(const bf16x8*)((char*)oL + byo);
        }
#pragma unroll
        for (int ct = 0; ct < 32; ++ct) {
            const u16* wsrc = Wf2p + (size_t)(16 * ct + l15) * 64 + lg * 8;
#pragma unroll
            for (int kf = 0; kf < 2; ++kf) {
                bf16x8 b = *(const bf16x8*)(wsrc + kf * 32);
                xa[ct] = __builtin_amdgcn_mfma_f32_16x16x32_bf16(a2[kf], b, xa[ct], 0, 0, 0);
            }
        }
#pragma unroll
        for (int ct = 0; ct < 32; ++ct) {
            int col = 16 * ct + l15;
            float bv = bf2[col];
#pragma unroll
            for (int i = 0; i < 4; ++i) {
                int lrow = 16 * wave + lg * 4 + i;
                float v = xa[ct][i] + bv;
                v = v > 0.f ? v : 0.f;
                int cb = col * 2;
                int byo = lrow * 1024 + (((cb & ~15) ^ ((lrow & 7) << 4)) | (cb & 15));
                *(u16*)((char*)xtL + byo) = f2bf(v);
            }
        }
        __syncthreads();
    }

    if (MODE <= 1) {
        // ---- gates: r,z over [xt||h] (K=1024); gi_n (K xt), gh_n (K h) ----
        f32x4 ar[4], az[4], agi[4], agh[4];
#pragma unroll
        for (int c = 0; c < 4; c++) {
            ar[c] = (f32x4){0.f, 0.f, 0.f, 0.f};
            az[c] = (f32x4){0.f, 0.f, 0.f, 0.f};
            agi[c] = (f32x4){0.f, 0.f, 0.f, 0.f};
            agh[c] = (f32x4){0.f, 0.f, 0.f, 0.f};
        }
        const int arow = 16 * wave + l15;  // this wave's A row (own 16 rows)
        for (int t = 0; t < 16; ++t) {
            // stage Bst(t): 24 chunks of 8 rows x 128B, src seg pre-swizzled
#pragma unroll
            for (int q = 0; q < 6; ++q) {
                int ch = q * 4 + wave;
                int rowin = lane >> 3, sseg = lane & 7;
                int row = ch * 8 + rowin;
                int gate = row >> 6, unit = row & 63;
                const u16* src = WB + (size_t)(gate * 512 + S + unit) * 1024 +
                                 t * 64 + (sseg ^ rowin) * 8;
                gload16(src, (char*)Bst + ch * 1024);
            }
            __syncthreads();
            bf16x8 a[2];
#pragma unroll
            for (int kf = 0; kf < 2; ++kf) {
                if (t < 8) {
                    int byo = arow * 1024 +
                              ((t * 128 + kf * 64 + lg * 16) ^ ((arow & 7) << 4));
                    a[kf] = *(const bf16x8*)((char*)xtL + byo);
                } else {
                    a[kf] = *(const bf16x8*)(hbR + (size_t)(m0 + arow) * 512 +
                                             (t - 8) * 64 + kf * 32 + lg * 8);
                }
            }
#pragma unroll
            for (int kf = 0; kf < 2; ++kf) {
#pragma unroll
                for (int c = 0; c < 4; ++c) {
                    int brow = 16 * c + l15;
                    int kby = (kf * 64 + lg * 16) ^ ((brow & 7) << 4);
                    bf16x8 br = *(const bf16x8*)((char*)Bst + brow * 128 + kby);
                    bf16x8 bz = *(const bf16x8*)((char*)Bst + (64 + brow) * 128 + kby);
                    bf16x8 bn = *(const bf16x8*)((char*)Bst + (128 + brow) * 128 + kby);
                    ar[c] = __builtin_amdgcn_mfma_f32_16x16x32_bf16(a[kf], br, ar[c], 0, 0, 0);
                    az[c] = __builtin_amdgcn_mfma_f32_16x16x32_bf16(a[kf], bz, az[c], 0, 0, 0);
                    if (t < 8)
                        agi[c] = __builtin_amdgcn_mfma_f32_16x16x32_bf16(a[kf], bn, agi[c], 0, 0, 0);
                    else
                        agh[c] = __builtin_amdgcn_mfma_f32_16x16x32_bf16(a[kf], bn, agh[c], 0, 0, 0);
                }
            }
            __syncthreads();
        }
        // GRU update epilogue
#pragma unroll
        for (int c = 0; c < 4; ++c) {
            int hu = S + 16 * c + l15;
            float br_ = bih[hu] + bhh[hu];
            float bz_ = bih[512 + hu] + bhh[512 + hu];
            float bgi = bih[1024 + hu];
            float bgh = bhh[1024 + hu];
#pragma unroll
            for (int i = 0; i < 4; ++i) {
                int grow = m0 + 16 * wave + lg * 4 + i;
                float rv = sigmoidf_(ar[c][i] + br_);
                float zv = sigmoidf_(az[c][i] + bz_);
                float nv = tanhf_(agi[c][i] + bgi + rv * (agh[c][i] + bgh));
                float hold = hfR[(size_t)grow * 512 + hu];
                float hn = (1.f - zv) * nv + zv * hold;
                hfW[(size_t)grow * 512 + hu] = hn;
                hbW[(size_t)grow * 512 + hu] = f2bf(hn);
            }
        }
    }
}

// ---------------------------------------------------------------------------
extern "C" void kernel_launch(void* const* d_in, const int* in_sizes, int n_in,
                              void* d_out, int out_size, void* d_ws,
                              size_t ws_size, hipStream_t stream) {
    (void)in_sizes; (void)n_in; (void)out_size;
    const float* x = (const float*)d_in[0];
    const float* eps = (const float*)d_in[2];
    const float* We1 = (const float*)d_in[3];
    const float* be1 = (const float*)d_in[4];
    const float* We2 = (const float*)d_in[5];
    const float* be2 = (const float*)d_in[6];
    const float* We3 = (const float*)d_in[7];
    const float* be3 = (const float*)d_in[8];
    const float* We41 = (const float*)d_in[9];
    const float* be41 = (const float*)d_in[10];
    const float* Wih = (const float*)d_in[11];
    const float* bih = (const float*)d_in[12];
    const float* Whh = (const float*)d_in[13];
    const float* bhh = (const float*)d_in[14];
    const float* Wf1 = (const float*)d_in[15];
    const float* bf1 = (const float*)d_in[16];
    const float* Wf2 = (const float*)d_in[17];
    const float* bf2 = (const float*)d_in[18];
    float* out = (float*)d_out;

    char* ws = (char*)d_ws;
    size_t off = 0;
    auto alloc = [&](size_t bytes) -> char* {
        char* p = ws + off;
        off += (bytes + 255) & ~(size_t)255;
        return p;
    };
    u16* xb = (u16*)alloc(2048ull * 4864 * 2);
    u16* We1b = (u16*)alloc(2048ull * 4864 * 2);
    u16* We2b = (u16*)alloc(1024ull * 2048 * 2);
    u16* We3b = (u16*)alloc(512ull * 1024 * 2);
    u16* We41b = (u16*)alloc(512ull * 512 * 2);
    u16* WB = (u16*)alloc(1536ull * 1024 * 2);
    u16* h1b = (u16*)alloc(2048ull * 2048 * 2);
    u16* h2b = (u16*)alloc(2048ull * 1024 * 2);
    u16* h3b = (u16*)alloc(2048ull * 512 * 2);
    u16* encb = (u16*)alloc(2048ull * 512 * 2);
    u16* hb0 = (u16*)alloc(2048ull * 512 * 2);
    u16* hb1 = (u16*)alloc(2048ull * 512 * 2);
    float* hf0 = (float*)alloc(2048ull * 512 * 4);
    float* hf1 = (float*)alloc(2048ull * 512 * 4);
    u16* Wf1p = (u16*)alloc(48ull * 512 * 2);
    u16* Wf2p = (u16*)alloc(512ull * 64 * 2);
    if (off > ws_size) {
        fill_const<<<(11010048 + 255) / 256, 256, 0, stream>>>(out, 11010048, 54321.0f);
        return;
    }
    u16* hb[2] = {hb0, hb1};
    float* hfl[2] = {hf0, hf1};

    auto cdiv = [](int a, int b) { return (a + b - 1) / b; };
    cvt_pad<<<dim3(cdiv(4864, 256), 2048), 256, 0, stream>>>(x, xb, 4864, 4860, 4860, 4864);
    cvt_pad<<<dim3(cdiv(4864, 256), 2048), 256, 0, stream>>>(We1, We1b, 4864, 4860, 4860, 4864);
    cvt_pad<<<dim3(cdiv(2048, 256), 1024), 256, 0, stream>>>(We2, We2b, 2048, 2048, 2048, 2048);
    cvt_pad<<<dim3(cdiv(1024, 256), 512), 256, 0, stream>>>(We3, We3b, 1024, 1024, 1024, 1024);
    cvt_pad<<<dim3(cdiv(512, 256), 512), 256, 0, stream>>>(We41, We41b, 512, 512, 512, 512);
    cvt_pad<<<dim3(cdiv(512, 256), 1536), 256, 0, stream>>>(Wih, WB, 512, 512, 512, 1024);
    cvt_pad<<<dim3(cdiv(512, 256), 1536), 256, 0, stream>>>(Whh, WB + 512, 512, 512, 512, 1024);
    prep_wf1<<<48, 512, 0, stream>>>(Wf1, Wf1p);
    prep_wf2<<<512, 64, 0, stream>>>(Wf2, Wf2p);
    hipMemsetAsync(hb0, 0, 2048ull * 512 * 2, stream);
    hipMemsetAsync(hf0, 0, 2048ull * 512 * 4, stream);

    // encoder (bf16 MFMA)
    gemm_bt<0><<<dim3(16, 16), 256, 0, stream>>>(xb, 4864, We1b, 4864, be1, h1b, 2048, 76, nullptr);
    gemm_bt<0><<<dim3(8, 16), 256, 0, stream>>>(h1b, 2048, We2b, 2048, be2, h2b, 1024, 32, nullptr);
    gemm_bt<0><<<dim3(4, 16), 256, 0, stream>>>(h2b, 1024, We3b, 1024, be3, h3b, 512, 16, nullptr);
    gemm_bt<1><<<dim3(4, 16), 256, 0, stream>>>(h3b, 512, We41b, 512, be41, encb, 512, 8, eps);

    // decoder: one fused kernel per step
    gru_step<0><<<dim3(8, 32), 256, 0, stream>>>(encb, hb0, hf0, hb1, hf1, WB, bih,
                                                 bhh, Wf1p, bf1, Wf2p, bf2, out, 0);
    for (int i = 1; i < 128; ++i) {
        int p = i & 1;
        gru_step<1><<<dim3(8, 32), 256, 0, stream>>>(nullptr, hb[p], hfl[p],
                                                     hb[p ^ 1], hfl[p ^ 1], WB, bih,
                                                     bhh, Wf1p, bf1, Wf2p, bf2, out,
                                                     i - 1);
    }
    gru_step<2><<<dim3(1, 32), 256, 0, stream>>>(nullptr, hb0, hf0, nullptr, nullptr,
                                                 WB, bih, bhh, Wf1p, bf1, Wf2p, bf2,
                                                 out, 127);
}

// Round 11
// 4950.306 us; speedup vs baseline: 13.1503x; 1.0309x over previous
//
#include <hip/hip_runtime.h>
#include <hip/hip_bf16.h>
#include <cstdint>
#include <cstddef>

#define DEVI __device__ __forceinline__

typedef __attribute__((ext_vector_type(8))) short bf16x8;
typedef __attribute__((ext_vector_type(4))) float f32x4;
typedef unsigned short u16;
typedef unsigned int u32;
typedef unsigned long long u64;

DEVI u16 f2bf(float f) {
    u32 i = __builtin_bit_cast(u32, f);
    u32 r = (i + 0x7FFFu + ((i >> 16) & 1u)) >> 16;
    return (u16)r;
}
DEVI float sigmoidf_(float x) { return 1.0f / (1.0f + __expf(-x)); }
DEVI float tanhf_(float x) { return 2.0f / (1.0f + __expf(-2.0f * x)) - 1.0f; }

typedef const __attribute__((address_space(1))) void* gptr_t;
typedef __attribute__((address_space(3))) void* lptr_t;

DEVI void gload16(const void* g, void* l) {
    __builtin_amdgcn_global_load_lds((gptr_t)g, (lptr_t)l, 16, 0, 0);
}

__global__ void fill_const(float* __restrict__ p, int n, float v) {
    int i = blockIdx.x * 256 + threadIdx.x;
    if (i < n) p[i] = v;
}

// ---------------- f32 -> bf16 convert (with optional zero K-padding) -------
__global__ void cvt_pad(const float* __restrict__ src, u16* __restrict__ dst,
                        int wcols, int cols, int spitch, int dpitch) {
    int c = blockIdx.x * 256 + threadIdx.x;
    int r = blockIdx.y;
    if (c >= wcols) return;
    float v = (c < cols) ? src[(size_t)r * spitch + c] : 0.0f;
    dst[(size_t)r * dpitch + c] = f2bf(v);
}

// ---------------- fc weight prep (bf16, zero-padded) -----------------------
__global__ void prep_wf1(const float* __restrict__ Wf1, u16* __restrict__ Wf1p) {
    int r = blockIdx.x;   // 0..47
    int c = threadIdx.x;  // 0..511
    Wf1p[r * 512 + c] = (r < 42) ? f2bf(Wf1[(size_t)r * 512 + c]) : (u16)0;
}
__global__ void prep_wf2(const float* __restrict__ Wf2, u16* __restrict__ Wf2p) {
    int c = blockIdx.x;   // 0..511
    int k = threadIdx.x;  // 0..63
    Wf2p[c * 64 + k] = (k < 42) ? f2bf(Wf2[(size_t)c * 42 + k]) : (u16)0;
}

// ---------------- encoder GEMM: C = epi(A @ B^T + bias) (validated) --------
template <int EPI>
__global__ __launch_bounds__(256) void gemm_bt(
    const u16* __restrict__ A, int lda, const u16* __restrict__ B, int ldb,
    const float* __restrict__ bias, u16* __restrict__ C, int ldc, int ktiles,
    const float* __restrict__ eps) {
    __shared__ u16 As[128 * 64];
    __shared__ u16 Bs[128 * 64];
    const int tid = threadIdx.x;
    const int lane = tid & 63;
    const int wave = tid >> 6;
    const int m0 = blockIdx.y * 128;
    const int n0 = blockIdx.x * 128;
    const int l15 = lane & 15, lg = lane >> 4;
    const int wm = (wave >> 1) * 64, wn = (wave & 1) * 64;

    f32x4 acc[4][4];
#pragma unroll
    for (int r = 0; r < 4; r++)
#pragma unroll
        for (int c = 0; c < 4; c++) acc[r][c] = (f32x4){0.f, 0.f, 0.f, 0.f};

    for (int t = 0; t < ktiles; ++t) {
        const int k0 = t * 64;
#pragma unroll
        for (int q = 0; q < 4; ++q) {
            int chunk = q * 4 + wave;
            int o = chunk * 1024 + lane * 16;
            int row = o >> 7;
            int cb = o & 127;
            gload16((const char*)(A + (size_t)(m0 + row) * lda + k0) + cb,
                    (char*)As + chunk * 1024);
            gload16((const char*)(B + (size_t)(n0 + row) * ldb + k0) + cb,
                    (char*)Bs + chunk * 1024);
        }
        __syncthreads();
#pragma unroll
        for (int kf = 0; kf < 2; ++kf) {
            bf16x8 a[4], b[4];
#pragma unroll
            for (int r = 0; r < 4; r++)
                a[r] = *(const bf16x8*)&As[(wm + 16 * r + l15) * 64 + kf * 32 + lg * 8];
#pragma unroll
            for (int c = 0; c < 4; c++)
                b[c] = *(const bf16x8*)&Bs[(wn + 16 * c + l15) * 64 + kf * 32 + lg * 8];
#pragma unroll
            for (int r = 0; r < 4; r++)
#pragma unroll
                for (int c = 0; c < 4; c++)
                    acc[r][c] = __builtin_amdgcn_mfma_f32_16x16x32_bf16(
                        a[r], b[c], acc[r][c], 0, 0, 0);
        }
        __syncthreads();
    }
#pragma unroll
    for (int r = 0; r < 4; r++) {
#pragma unroll
        for (int c = 0; c < 4; c++) {
            int col = n0 + wn + 16 * c + l15;
            float bv = bias[col];
#pragma unroll
            for (int i = 0; i < 4; i++) {
                int row = m0 + wm + 16 * r + lg * 4 + i;
                float v = acc[r][c][i] + bv;
                if (EPI == 0) {
                    v = v > 0.f ? v : 0.f;
                    C[(size_t)row * ldc + col] = f2bf(v);
                } else {
                    float e = eps[(size_t)row * 512 + col];
                    float enc = e * __expf(0.5f * v) + v;
                    C[(size_t)row * ldc + col] = f2bf(enc);
                }
            }
        }
    }
}

// ================= FUSED PER-STEP DECODER (1024 thr, 16 waves) =============
// Block (sb=blockIdx.x, rb=blockIdx.y): 64 rows (m0), 64 units (S).
// Wave (wr=wave>>2, wu=wave&3): 16 rows x 16 units.
// MODE 0: stage xt=enc into LDS; gates only.
// MODE 1: fc1(h)->out+oL; fc2(oL)->xtL; gates(xtL,h)->h'.
// MODE 2: fc1(h)->out only (grid (1,32)).
// All LDS tiles XOR-swizzled: byte ^= ((row&7)<<4). Bst double-buffered.
template <int MODE>
__global__ __launch_bounds__(1024, 1) void gru_step(
    const u16* __restrict__ xt0, const u16* __restrict__ hbR,
    const float* __restrict__ hfR, u16* __restrict__ hbW,
    float* __restrict__ hfW, const u16* __restrict__ WB,
    const float* __restrict__ bih, const float* __restrict__ bhh,
    const u16* __restrict__ Wf1p, const float* __restrict__ bf1,
    const u16* __restrict__ Wf2p, const float* __restrict__ bf2,
    float* __restrict__ outp, int sidx) {
    __shared__ __align__(16) u16 xtL[64 * 512];   // 64KB swizzled xt tile
    __shared__ __align__(16) u16 Bst[2][192 * 64];  // 2x24KB gate-W dbuf
    __shared__ __align__(16) u16 oL[64 * 64];     // 8KB fc1-out tile
    const int tid = threadIdx.x, lane = tid & 63, wave = tid >> 6;
    const int wr = wave >> 2, wu = wave & 3;
    const int l15 = lane & 15, lg = lane >> 4;
    const int S = blockIdx.x * 64, m0 = blockIdx.y * 64;

    if (MODE == 0) {
        // stage xtL from encoded: 4096 16B issues, src slot pre-swizzled
#pragma unroll
        for (int k2 = 0; k2 < 4; ++k2) {
            int j = tid + k2 * 1024;
            int row = j >> 6, slot = j & 63;
            gload16((const char*)(xt0 + (size_t)(m0 + row) * 512) + (slot ^ (row & 7)) * 16,
                    (char*)xtL + j * 16);
        }
    }

    if (MODE >= 1) {
        if (MODE == 1) {
            ((u64*)oL)[tid] = 0ull;  // zero incl. pad cols 48..63
            __syncthreads();
        }
        // ---- fc1: 16 rows x 16 cols per wave (wu<3) ----
        if (wu < 3) {
            f32x4 oa = (f32x4){0.f, 0.f, 0.f, 0.f};
            const u16* ha = hbR + (size_t)(m0 + 16 * wr + l15) * 512 + lg * 8;
            const u16* wb1 = Wf1p + (size_t)(16 * wu + l15) * 512 + lg * 8;
#pragma unroll
            for (int kf = 0; kf < 16; ++kf) {
                bf16x8 a = *(const bf16x8*)(ha + kf * 32);
                bf16x8 b = *(const bf16x8*)(wb1 + kf * 32);
                oa = __builtin_amdgcn_mfma_f32_16x16x32_bf16(a, b, oa, 0, 0, 0);
            }
            int col = 16 * wu + l15;
            float bv = (col < 42) ? bf1[col] : 0.f;
#pragma unroll
            for (int i = 0; i < 4; ++i) {
                int row = 16 * wr + lg * 4 + i;
                float v = oa[i] + bv;
                v = v > 0.f ? v : 0.f;
                if (MODE == 1) {
                    int cb = col * 2;
                    *(u16*)((char*)oL + row * 128 +
                            (((cb & ~15) ^ ((row & 7) << 4)) | (cb & 15))) = f2bf(v);
                }
                if (blockIdx.x == 0 && col < 42)
                    outp[(size_t)(m0 + row) * 5376 + (size_t)sidx * 42 + col] = v;
            }
        }
    }

    if (MODE == 1) {
        __syncthreads();  // oL complete
        // ---- fc2: 16 rows x 128 cols per wave -> xtL ----
        bf16x8 a2[2];
#pragma unroll
        for (int kf = 0; kf < 2; ++kf) {
            int row = 16 * wr + l15;
            a2[kf] = *(const bf16x8*)((char*)oL + row * 128 +
                                      ((kf * 64 + lg * 16) ^ ((row & 7) << 4)));
        }
#pragma unroll
        for (int ci = 0; ci < 8; ++ci) {
            int col = 128 * wu + 16 * ci + l15;
            const u16* wb2 = Wf2p + (size_t)col * 64 + lg * 8;
            f32x4 xa = (f32x4){0.f, 0.f, 0.f, 0.f};
            xa = __builtin_amdgcn_mfma_f32_16x16x32_bf16(a2[0], *(const bf16x8*)wb2, xa, 0, 0, 0);
            xa = __builtin_amdgcn_mfma_f32_16x16x32_bf16(a2[1], *(const bf16x8*)(wb2 + 32), xa, 0, 0, 0);
            float bv = bf2[col];
            int cb = col * 2;
#pragma unroll
            for (int i = 0; i < 4; ++i) {
                int row = 16 * wr + lg * 4 + i;
                float v = xa[i] + bv;
                v = v > 0.f ? v : 0.f;
                *(u16*)((char*)xtL + row * 1024 +
                        (((cb & ~15) ^ ((row & 7) << 4)) | (cb & 15))) = f2bf(v);
            }
        }
    }

    if (MODE <= 1) {
        // ---- gates: r,z over [xt||h]; gi_n (t<8), gh_n (t>=8) ----
        auto stageB = [&](int buf, int t) {
            {
                int j = tid;
                int row = j >> 3, slot = j & 7;
                int gate = row >> 6, unit = row & 63;
                gload16(WB + (size_t)(gate * 512 + S + unit) * 1024 + t * 64 +
                            (slot ^ (row & 7)) * 8,
                        (char*)Bst + buf * 24576 + j * 16);
            }
            if (tid < 512) {
                int j = tid + 1024;
                int row = j >> 3, slot = j & 7;
                int gate = row >> 6, unit = row & 63;
                gload16(WB + (size_t)(gate * 512 + S + unit) * 1024 + t * 64 +
                            (slot ^ (row & 7)) * 8,
                        (char*)Bst + buf * 24576 + j * 16);
            }
        };
        f32x4 ar = (f32x4){0.f, 0.f, 0.f, 0.f};
        f32x4 az = ar, agi = ar, agh = ar;
        const u16* hrow = hbR + (size_t)(m0 + 16 * wr + l15) * 512 + lg * 8;
        bf16x8 hc0, hc1, hp0, hp1;

        stageB(0, 0);
        __syncthreads();  // xtL (MODE0 stage or fc2 writes) + Bst buf0 ready

        for (int t = 0; t < 16; ++t) {
            // prefetch h-frags for t+1 (global, flies under compute)
            if (t >= 7 && t < 15) {
                const u16* hs = hrow + (t + 1 - 8) * 64;
                hp0 = *(const bf16x8*)hs;
                hp1 = *(const bf16x8*)(hs + 32);
            }
            if (t < 15) stageB((t + 1) & 1, t + 1);

            bf16x8 a[2];
            if (t < 8) {
                int row = 16 * wr + l15;
#pragma unroll
                for (int kf = 0; kf < 2; ++kf)
                    a[kf] = *(const bf16x8*)((char*)xtL + row * 1024 +
                                             ((t * 128 + kf * 64 + lg * 16) ^ ((row & 7) << 4)));
            } else {
                a[0] = hc0;
                a[1] = hc1;
            }
            const char* bb = (const char*)Bst + (t & 1) * 24576;
            int rb0 = 16 * wu + l15;
            int sw = (rb0 & 7) << 4;
#pragma unroll
            for (int kf = 0; kf < 2; ++kf) {
                int kb = kf * 64 + lg * 16;
                bf16x8 br = *(const bf16x8*)(bb + (size_t)rb0 * 128 + (kb ^ sw));
                bf16x8 bz = *(const bf16x8*)(bb + (size_t)(64 + rb0) * 128 + (kb ^ sw));
                bf16x8 bn = *(const bf16x8*)(bb + (size_t)(128 + rb0) * 128 + (kb ^ sw));
                ar = __builtin_amdgcn_mfma_f32_16x16x32_bf16(a[kf], br, ar, 0, 0, 0);
                az = __builtin_amdgcn_mfma_f32_16x16x32_bf16(a[kf], bz, az, 0, 0, 0);
                if (t < 8)
                    agi = __builtin_amdgcn_mfma_f32_16x16x32_bf16(a[kf], bn, agi, 0, 0, 0);
                else
                    agh = __builtin_amdgcn_mfma_f32_16x16x32_bf16(a[kf], bn, agh, 0, 0, 0);
            }
            hc0 = hp0;
            hc1 = hp1;
            __syncthreads();
        }
        // ---- GRU update epilogue ----
        int hu = S + 16 * wu + l15;
        float br_ = bih[hu] + bhh[hu];
        float bz_ = bih[512 + hu] + bhh[512 + hu];
        float bgi = bih[1024 + hu];
        float bgh = bhh[1024 + hu];
#pragma unroll
        for (int i = 0; i < 4; ++i) {
            int row = m0 + 16 * wr + lg * 4 + i;
            float rv = sigmoidf_(ar[i] + br_);
            float zv = sigmoidf_(az[i] + bz_);
            float nv = tanhf_(agi[i] + bgi + rv * (agh[i] + bgh));
            float hold = hfR[(size_t)row * 512 + hu];
            float hn = (1.f - zv) * nv + zv * hold;
            hfW[(size_t)row * 512 + hu] = hn;
            hbW[(size_t)row * 512 + hu] = f2bf(hn);
        }
    }
}

// ---------------------------------------------------------------------------
extern "C" void kernel_launch(void* const* d_in, const int* in_sizes, int n_in,
                              void* d_out, int out_size, void* d_ws,
                              size_t ws_size, hipStream_t stream) {
    (void)in_sizes; (void)n_in; (void)out_size;
    const float* x = (const float*)d_in[0];
    const float* eps = (const float*)d_in[2];
    const float* We1 = (const float*)d_in[3];
    const float* be1 = (const float*)d_in[4];
    const float* We2 = (const float*)d_in[5];
    const float* be2 = (const float*)d_in[6];
    const float* We3 = (const float*)d_in[7];
    const float* be3 = (const float*)d_in[8];
    const float* We41 = (const float*)d_in[9];
    const float* be41 = (const float*)d_in[10];
    const float* Wih = (const float*)d_in[11];
    const float* bih = (const float*)d_in[12];
    const float* Whh = (const float*)d_in[13];
    const float* bhh = (const float*)d_in[14];
    const float* Wf1 = (const float*)d_in[15];
    const float* bf1 = (const float*)d_in[16];
    const float* Wf2 = (const float*)d_in[17];
    const float* bf2 = (const float*)d_in[18];
    float* out = (float*)d_out;

    char* ws = (char*)d_ws;
    size_t off = 0;
    auto alloc = [&](size_t bytes) -> char* {
        char* p = ws + off;
        off += (bytes + 255) & ~(size_t)255;
        return p;
    };
    u16* xb = (u16*)alloc(2048ull * 4864 * 2);
    u16* We1b = (u16*)alloc(2048ull * 4864 * 2);
    u16* We2b = (u16*)alloc(1024ull * 2048 * 2);
    u16* We3b = (u16*)alloc(512ull * 1024 * 2);
    u16* We41b = (u16*)alloc(512ull * 512 * 2);
    u16* WB = (u16*)alloc(1536ull * 1024 * 2);
    u16* h1b = (u16*)alloc(2048ull * 2048 * 2);
    u16* h2b = (u16*)alloc(2048ull * 1024 * 2);
    u16* h3b = (u16*)alloc(2048ull * 512 * 2);
    u16* encb = (u16*)alloc(2048ull * 512 * 2);
    u16* hb0 = (u16*)alloc(2048ull * 512 * 2);
    u16* hb1 = (u16*)alloc(2048ull * 512 * 2);
    float* hf0 = (float*)alloc(2048ull * 512 * 4);
    float* hf1 = (float*)alloc(2048ull * 512 * 4);
    u16* Wf1p = (u16*)alloc(48ull * 512 * 2);
    u16* Wf2p = (u16*)alloc(512ull * 64 * 2);
    if (off > ws_size) {
        fill_const<<<(11010048 + 255) / 256, 256, 0, stream>>>(out, 11010048, 54321.0f);
        return;
    }
    u16* hb[2] = {hb0, hb1};
    float* hfl[2] = {hf0, hf1};

    auto cdiv = [](int a, int b) { return (a + b - 1) / b; };
    cvt_pad<<<dim3(cdiv(4864, 256), 2048), 256, 0, stream>>>(x, xb, 4864, 4860, 4860, 4864);
    cvt_pad<<<dim3(cdiv(4864, 256), 2048), 256, 0, stream>>>(We1, We1b, 4864, 4860, 4860, 4864);
    cvt_pad<<<dim3(cdiv(2048, 256), 1024), 256, 0, stream>>>(We2, We2b, 2048, 2048, 2048, 2048);
    cvt_pad<<<dim3(cdiv(1024, 256), 512), 256, 0, stream>>>(We3, We3b, 1024, 1024, 1024, 1024);
    cvt_pad<<<dim3(cdiv(512, 256), 512), 256, 0, stream>>>(We41, We41b, 512, 512, 512, 512);
    cvt_pad<<<dim3(cdiv(512, 256), 1536), 256, 0, stream>>>(Wih, WB, 512, 512, 512, 1024);
    cvt_pad<<<dim3(cdiv(512, 256), 1536), 256, 0, stream>>>(Whh, WB + 512, 512, 512, 512, 1024);
    prep_wf1<<<48, 512, 0, stream>>>(Wf1, Wf1p);
    prep_wf2<<<512, 64, 0, stream>>>(Wf2, Wf2p);
    hipMemsetAsync(hb0, 0, 2048ull * 512 * 2, stream);
    hipMemsetAsync(hf0, 0, 2048ull * 512 * 4, stream);

    // encoder (bf16 MFMA)
    gemm_bt<0><<<dim3(16, 16), 256, 0, stream>>>(xb, 4864, We1b, 4864, be1, h1b, 2048, 76, nullptr);
    gemm_bt<0><<<dim3(8, 16), 256, 0, stream>>>(h1b, 2048, We2b, 2048, be2, h2b, 1024, 32, nullptr);
    gemm_bt<0><<<dim3(4, 16), 256, 0, stream>>>(h2b, 1024, We3b, 1024, be3, h3b, 512, 16, nullptr);
    gemm_bt<1><<<dim3(4, 16), 256, 0, stream>>>(h3b, 512, We41b, 512, be41, encb, 512, 8, eps);

    // decoder: one fused kernel per step (1024 threads, 16 waves)
    gru_step<0><<<dim3(8, 32), 1024, 0, stream>>>(encb, hb0, hf0, hb1, hf1, WB, bih,
                                                  bhh, Wf1p, bf1, Wf2p, bf2, out, 0);
    for (int i = 1; i < 128; ++i) {
        int p = i & 1;
        gru_step<1><<<dim3(8, 32), 1024, 0, stream>>>(nullptr, hb[p], hfl[p],
                                                      hb[p ^ 1], hfl[p ^ 1], WB, bih,
                                                      bhh, Wf1p, bf1, Wf2p, bf2, out,
                                                      i - 1);
    }
    gru_step<2><<<dim3(1, 32), 1024, 0, stream>>>(nullptr, hb0, hf0, nullptr, nullptr,
                                                  WB, bih, bhh, Wf1p, bf1, Wf2p, bf2,
                                                  out, 127);
}

// Round 12
// 4946.994 us; speedup vs baseline: 13.1591x; 1.0007x over previous
//
#include <hip/hip_runtime.h>
#include <hip/hip_bf16.h>
#include <cstdint>
#include <cstddef>

#define DEVI __device__ __forceinline__

typedef __attribute__((ext_vector_type(8))) short bf16x8;
typedef __attribute__((ext_vector_type(4))) float f32x4;
typedef unsigned short u16;
typedef unsigned int u32;
typedef unsigned long long u64;

DEVI u16 f2bf(float f) {
    u32 i = __builtin_bit_cast(u32, f);
    u32 r = (i + 0x7FFFu + ((i >> 16) & 1u)) >> 16;
    return (u16)r;
}
DEVI float sigmoidf_(float x) { return 1.0f / (1.0f + __expf(-x)); }
DEVI float tanhf_(float x) { return 2.0f / (1.0f + __expf(-2.0f * x)) - 1.0f; }

typedef const __attribute__((address_space(1))) void* gptr_t;
typedef __attribute__((address_space(3))) void* lptr_t;

DEVI void gload16(const void* g, void* l) {
    __builtin_amdgcn_global_load_lds((gptr_t)g, (lptr_t)l, 16, 0, 0);
}

__global__ void fill_const(float* __restrict__ p, int n, float v) {
    int i = blockIdx.x * 256 + threadIdx.x;
    if (i < n) p[i] = v;
}

// ---------------- f32 -> bf16 convert (with optional zero K-padding) -------
__global__ void cvt_pad(const float* __restrict__ src, u16* __restrict__ dst,
                        int wcols, int cols, int spitch, int dpitch) {
    int c = blockIdx.x * 256 + threadIdx.x;
    int r = blockIdx.y;
    if (c >= wcols) return;
    float v = (c < cols) ? src[(size_t)r * spitch + c] : 0.0f;
    dst[(size_t)r * dpitch + c] = f2bf(v);
}

// ---------------- fc weight prep (bf16, zero-padded) -----------------------
__global__ void prep_wf1(const float* __restrict__ Wf1, u16* __restrict__ Wf1p) {
    int r = blockIdx.x;   // 0..47
    int c = threadIdx.x;  // 0..511
    Wf1p[r * 512 + c] = (r < 42) ? f2bf(Wf1[(size_t)r * 512 + c]) : (u16)0;
}
__global__ void prep_wf2(const float* __restrict__ Wf2, u16* __restrict__ Wf2p) {
    int c = blockIdx.x;   // 0..511
    int k = threadIdx.x;  // 0..63
    Wf2p[c * 64 + k] = (k < 42) ? f2bf(Wf2[(size_t)c * 42 + k]) : (u16)0;
}

// ---------------- encoder GEMM: C = epi(A @ B^T + bias) (validated) --------
template <int EPI>
__global__ __launch_bounds__(256) void gemm_bt(
    const u16* __restrict__ A, int lda, const u16* __restrict__ B, int ldb,
    const float* __restrict__ bias, u16* __restrict__ C, int ldc, int ktiles,
    const float* __restrict__ eps) {
    __shared__ u16 As[128 * 64];
    __shared__ u16 Bs[128 * 64];
    const int tid = threadIdx.x;
    const int lane = tid & 63;
    const int wave = tid >> 6;
    const int m0 = blockIdx.y * 128;
    const int n0 = blockIdx.x * 128;
    const int l15 = lane & 15, lg = lane >> 4;
    const int wm = (wave >> 1) * 64, wn = (wave & 1) * 64;

    f32x4 acc[4][4];
#pragma unroll
    for (int r = 0; r < 4; r++)
#pragma unroll
        for (int c = 0; c < 4; c++) acc[r][c] = (f32x4){0.f, 0.f, 0.f, 0.f};

    for (int t = 0; t < ktiles; ++t) {
        const int k0 = t * 64;
#pragma unroll
        for (int q = 0; q < 4; ++q) {
            int chunk = q * 4 + wave;
            int o = chunk * 1024 + lane * 16;
            int row = o >> 7;
            int cb = o & 127;
            gload16((const char*)(A + (size_t)(m0 + row) * lda + k0) + cb,
                    (char*)As + chunk * 1024);
            gload16((const char*)(B + (size_t)(n0 + row) * ldb + k0) + cb,
                    (char*)Bs + chunk * 1024);
        }
        __syncthreads();
#pragma unroll
        for (int kf = 0; kf < 2; ++kf) {
            bf16x8 a[4], b[4];
#pragma unroll
            for (int r = 0; r < 4; r++)
                a[r] = *(const bf16x8*)&As[(wm + 16 * r + l15) * 64 + kf * 32 + lg * 8];
#pragma unroll
            for (int c = 0; c < 4; c++)
                b[c] = *(const bf16x8*)&Bs[(wn + 16 * c + l15) * 64 + kf * 32 + lg * 8];
#pragma unroll
            for (int r = 0; r < 4; r++)
#pragma unroll
                for (int c = 0; c < 4; c++)
                    acc[r][c] = __builtin_amdgcn_mfma_f32_16x16x32_bf16(
                        a[r], b[c], acc[r][c], 0, 0, 0);
        }
        __syncthreads();
    }
#pragma unroll
    for (int r = 0; r < 4; r++) {
#pragma unroll
        for (int c = 0; c < 4; c++) {
            int col = n0 + wn + 16 * c + l15;
            float bv = bias[col];
#pragma unroll
            for (int i = 0; i < 4; i++) {
                int row = m0 + wm + 16 * r + lg * 4 + i;
                float v = acc[r][c][i] + bv;
                if (EPI == 0) {
                    v = v > 0.f ? v : 0.f;
                    C[(size_t)row * ldc + col] = f2bf(v);
                } else {
                    float e = eps[(size_t)row * 512 + col];
                    float enc = e * __expf(0.5f * v) + v;
                    C[(size_t)row * ldc + col] = f2bf(enc);
                }
            }
        }
    }
}

// ================= FUSED PER-STEP DECODER (1024 thr, 16 waves) =============
// Linear grid 256; XCD-aware: sb = bid & 7 (consecutive bids round-robin
// XCDs, so all 32 row-blocks sharing one WB slice land on ONE XCD => the
// slice + fc weights stay L2-resident instead of being re-pulled from L3).
// Wave (wr=wave>>2, wu=wave&3): 16 rows x 16 units.
// MODE 0: stage xt=enc into LDS; gates only.
// MODE 1: fc1(h)->out+oL; fc2(oL)->xtL; gates(xtL,h)->h'.
// MODE 2: fc1(h)->out only (32 blocks).
template <int MODE>
__global__ __launch_bounds__(1024, 1) void gru_step(
    const u16* __restrict__ xt0, const u16* __restrict__ hbR,
    const float* __restrict__ hfR, u16* __restrict__ hbW,
    float* __restrict__ hfW, const u16* __restrict__ WB,
    const float* __restrict__ bih, const float* __restrict__ bhh,
    const u16* __restrict__ Wf1p, const float* __restrict__ bf1,
    const u16* __restrict__ Wf2p, const float* __restrict__ bf2,
    float* __restrict__ outp, int sidx) {
    __shared__ __align__(16) u16 xtL[64 * 512];     // 64KB swizzled xt tile
    __shared__ __align__(16) u16 Bst[2][192 * 64];  // 2x24KB gate-W dbuf
    __shared__ __align__(16) u16 oL[64 * 64];       // 8KB fc1-out tile
    const int tid = threadIdx.x, lane = tid & 63, wave = tid >> 6;
    const int wr = wave >> 2, wu = wave & 3;
    const int l15 = lane & 15, lg = lane >> 4;
    const int bid = blockIdx.x;
    const int sb = (MODE == 2) ? 0 : (bid & 7);
    const int rb = (MODE == 2) ? bid : (bid >> 3);
    const int S = sb * 64, m0 = rb * 64;

    if (MODE == 0) {
        // stage xtL from encoded: 4096 16B issues, src slot pre-swizzled
#pragma unroll
        for (int k2 = 0; k2 < 4; ++k2) {
            int j = tid + k2 * 1024;
            int row = j >> 6, slot = j & 63;
            gload16((const char*)(xt0 + (size_t)(m0 + row) * 512) + (slot ^ (row & 7)) * 16,
                    (char*)xtL + j * 16);
        }
    }

    if (MODE >= 1) {
        if (MODE == 1) {
            ((u64*)oL)[tid] = 0ull;  // zero incl. pad cols 48..63
            __syncthreads();
        }
        // ---- fc1: 16 rows x 16 cols per wave (wu<3) ----
        if (wu < 3) {
            f32x4 oa = (f32x4){0.f, 0.f, 0.f, 0.f};
            const u16* ha = hbR + (size_t)(m0 + 16 * wr + l15) * 512 + lg * 8;
            const u16* wb1 = Wf1p + (size_t)(16 * wu + l15) * 512 + lg * 8;
#pragma unroll
            for (int kf = 0; kf < 16; ++kf) {
                bf16x8 a = *(const bf16x8*)(ha + kf * 32);
                bf16x8 b = *(const bf16x8*)(wb1 + kf * 32);
                oa = __builtin_amdgcn_mfma_f32_16x16x32_bf16(a, b, oa, 0, 0, 0);
            }
            int col = 16 * wu + l15;
            float bv = (col < 42) ? bf1[col] : 0.f;
#pragma unroll
            for (int i = 0; i < 4; ++i) {
                int row = 16 * wr + lg * 4 + i;
                float v = oa[i] + bv;
                v = v > 0.f ? v : 0.f;
                if (MODE == 1) {
                    int cb = col * 2;
                    *(u16*)((char*)oL + row * 128 +
                            (((cb & ~15) ^ ((row & 7) << 4)) | (cb & 15))) = f2bf(v);
                }
                if (sb == 0 && col < 42)
                    outp[(size_t)(m0 + row) * 5376 + (size_t)sidx * 42 + col] = v;
            }
        }
    }

    if (MODE == 1) {
        __syncthreads();  // oL complete
        // ---- fc2: 16 rows x 128 cols per wave -> xtL ----
        bf16x8 a2[2];
#pragma unroll
        for (int kf = 0; kf < 2; ++kf) {
            int row = 16 * wr + l15;
            a2[kf] = *(const bf16x8*)((char*)oL + row * 128 +
                                      ((kf * 64 + lg * 16) ^ ((row & 7) << 4)));
        }
#pragma unroll
        for (int ci = 0; ci < 8; ++ci) {
            int col = 128 * wu + 16 * ci + l15;
            const u16* wb2 = Wf2p + (size_t)col * 64 + lg * 8;
            f32x4 xa = (f32x4){0.f, 0.f, 0.f, 0.f};
            xa = __builtin_amdgcn_mfma_f32_16x16x32_bf16(a2[0], *(const bf16x8*)wb2, xa, 0, 0, 0);
            xa = __builtin_amdgcn_mfma_f32_16x16x32_bf16(a2[1], *(const bf16x8*)(wb2 + 32), xa, 0, 0, 0);
            float bv = bf2[col];
            int cb = col * 2;
#pragma unroll
            for (int i = 0; i < 4; ++i) {
                int row = 16 * wr + lg * 4 + i;
                float v = xa[i] + bv;
                v = v > 0.f ? v : 0.f;
                *(u16*)((char*)xtL + row * 1024 +
                        (((cb & ~15) ^ ((row & 7) << 4)) | (cb & 15))) = f2bf(v);
            }
        }
    }

    if (MODE <= 1) {
        // ---- gates: r,z over [xt||h]; gi_n (t<8), gh_n (t>=8) ----
        auto stageB = [&](int buf, int t) {
            {
                int j = tid;
                int row = j >> 3, slot = j & 7;
                int gate = row >> 6, unit = row & 63;
                gload16(WB + (size_t)(gate * 512 + S + unit) * 1024 + t * 64 +
                            (slot ^ (row & 7)) * 8,
                        (char*)Bst + buf * 24576 + j * 16);
            }
            if (tid < 512) {
                int j = tid + 1024;
                int row = j >> 3, slot = j & 7;
                int gate = row >> 6, unit = row & 63;
                gload16(WB + (size_t)(gate * 512 + S + unit) * 1024 + t * 64 +
                            (slot ^ (row & 7)) * 8,
                        (char*)Bst + buf * 24576 + j * 16);
            }
        };
        f32x4 ar = (f32x4){0.f, 0.f, 0.f, 0.f};
        f32x4 az = ar, agi = ar, agh = ar;
        const u16* hrow = hbR + (size_t)(m0 + 16 * wr + l15) * 512 + lg * 8;
        bf16x8 hc0, hc1, hp0, hp1;

        stageB(0, 0);
        __syncthreads();  // xtL (MODE0 stage or fc2 writes) + Bst buf0 ready

        for (int t = 0; t < 16; ++t) {
            // prefetch h-frags for t+1 (global, flies under compute)
            if (t >= 7 && t < 15) {
                const u16* hs = hrow + (t + 1 - 8) * 64;
                hp0 = *(const bf16x8*)hs;
                hp1 = *(const bf16x8*)(hs + 32);
            }
            if (t < 15) stageB((t + 1) & 1, t + 1);

            bf16x8 a[2];
            if (t < 8) {
                int row = 16 * wr + l15;
#pragma unroll
                for (int kf = 0; kf < 2; ++kf)
                    a[kf] = *(const bf16x8*)((char*)xtL + row * 1024 +
                                             ((t * 128 + kf * 64 + lg * 16) ^ ((row & 7) << 4)));
            } else {
                a[0] = hc0;
                a[1] = hc1;
            }
            const char* bb = (const char*)Bst + (t & 1) * 24576;
            int rb0 = 16 * wu + l15;
            int sw = (rb0 & 7) << 4;
#pragma unroll
            for (int kf = 0; kf < 2; ++kf) {
                int kb = kf * 64 + lg * 16;
                bf16x8 br = *(const bf16x8*)(bb + (size_t)rb0 * 128 + (kb ^ sw));
                bf16x8 bz = *(const bf16x8*)(bb + (size_t)(64 + rb0) * 128 + (kb ^ sw));
                bf16x8 bn = *(const bf16x8*)(bb + (size_t)(128 + rb0) * 128 + (kb ^ sw));
                ar = __builtin_amdgcn_mfma_f32_16x16x32_bf16(a[kf], br, ar, 0, 0, 0);
                az = __builtin_amdgcn_mfma_f32_16x16x32_bf16(a[kf], bz, az, 0, 0, 0);
                if (t < 8)
                    agi = __builtin_amdgcn_mfma_f32_16x16x32_bf16(a[kf], bn, agi, 0, 0, 0);
                else
                    agh = __builtin_amdgcn_mfma_f32_16x16x32_bf16(a[kf], bn, agh, 0, 0, 0);
            }
            hc0 = hp0;
            hc1 = hp1;
            __syncthreads();
        }
        // ---- GRU update epilogue ----
        int hu = S + 16 * wu + l15;
        float br_ = bih[hu] + bhh[hu];
        float bz_ = bih[512 + hu] + bhh[512 + hu];
        float bgi = bih[1024 + hu];
        float bgh = bhh[1024 + hu];
#pragma unroll
        for (int i = 0; i < 4; ++i) {
            int row = m0 + 16 * wr + lg * 4 + i;
            float rv = sigmoidf_(ar[i] + br_);
            float zv = sigmoidf_(az[i] + bz_);
            float nv = tanhf_(agi[i] + bgi + rv * (agh[i] + bgh));
            float hold = hfR[(size_t)row * 512 + hu];
            float hn = (1.f - zv) * nv + zv * hold;
            hfW[(size_t)row * 512 + hu] = hn;
            hbW[(size_t)row * 512 + hu] = f2bf(hn);
        }
    }
}

// ---------------------------------------------------------------------------
extern "C" void kernel_launch(void* const* d_in, const int* in_sizes, int n_in,
                              void* d_out, int out_size, void* d_ws,
                              size_t ws_size, hipStream_t stream) {
    (void)in_sizes; (void)n_in; (void)out_size;
    const float* x = (const float*)d_in[0];
    const float* eps = (const float*)d_in[2];
    const float* We1 = (const float*)d_in[3];
    const float* be1 = (const float*)d_in[4];
    const float* We2 = (const float*)d_in[5];
    const float* be2 = (const float*)d_in[6];
    const float* We3 = (const float*)d_in[7];
    const float* be3 = (const float*)d_in[8];
    const float* We41 = (const float*)d_in[9];
    const float* be41 = (const float*)d_in[10];
    const float* Wih = (const float*)d_in[11];
    const float* bih = (const float*)d_in[12];
    const float* Whh = (const float*)d_in[13];
    const float* bhh = (const float*)d_in[14];
    const float* Wf1 = (const float*)d_in[15];
    const float* bf1 = (const float*)d_in[16];
    const float* Wf2 = (const float*)d_in[17];
    const float* bf2 = (const float*)d_in[18];
    float* out = (float*)d_out;

    char* ws = (char*)d_ws;
    size_t off = 0;
    auto alloc = [&](size_t bytes) -> char* {
        char* p = ws + off;
        off += (bytes + 255) & ~(size_t)255;
        return p;
    };
    u16* xb = (u16*)alloc(2048ull * 4864 * 2);
    u16* We1b = (u16*)alloc(2048ull * 4864 * 2);
    u16* We2b = (u16*)alloc(1024ull * 2048 * 2);
    u16* We3b = (u16*)alloc(512ull * 1024 * 2);
    u16* We41b = (u16*)alloc(512ull * 512 * 2);
    u16* WB = (u16*)alloc(1536ull * 1024 * 2);
    u16* h1b = (u16*)alloc(2048ull * 2048 * 2);
    u16* h2b = (u16*)alloc(2048ull * 1024 * 2);
    u16* h3b = (u16*)alloc(2048ull * 512 * 2);
    u16* encb = (u16*)alloc(2048ull * 512 * 2);
    u16* hb0 = (u16*)alloc(2048ull * 512 * 2);
    u16* hb1 = (u16*)alloc(2048ull * 512 * 2);
    float* hf0 = (float*)alloc(2048ull * 512 * 4);
    float* hf1 = (float*)alloc(2048ull * 512 * 4);
    u16* Wf1p = (u16*)alloc(48ull * 512 * 2);
    u16* Wf2p = (u16*)alloc(512ull * 64 * 2);
    if (off > ws_size) {
        fill_const<<<(11010048 + 255) / 256, 256, 0, stream>>>(out, 11010048, 54321.0f);
        return;
    }
    u16* hb[2] = {hb0, hb1};
    float* hfl[2] = {hf0, hf1};

    auto cdiv = [](int a, int b) { return (a + b - 1) / b; };
    cvt_pad<<<dim3(cdiv(4864, 256), 2048), 256, 0, stream>>>(x, xb, 4864, 4860, 4860, 4864);
    cvt_pad<<<dim3(cdiv(4864, 256), 2048), 256, 0, stream>>>(We1, We1b, 4864, 4860, 4860, 4864);
    cvt_pad<<<dim3(cdiv(2048, 256), 1024), 256, 0, stream>>>(We2, We2b, 2048, 2048, 2048, 2048);
    cvt_pad<<<dim3(cdiv(1024, 256), 512), 256, 0, stream>>>(We3, We3b, 1024, 1024, 1024, 1024);
    cvt_pad<<<dim3(cdiv(512, 256), 512), 256, 0, stream>>>(We41, We41b, 512, 512, 512, 512);
    cvt_pad<<<dim3(cdiv(512, 256), 1536), 256, 0, stream>>>(Wih, WB, 512, 512, 512, 1024);
    cvt_pad<<<dim3(cdiv(512, 256), 1536), 256, 0, stream>>>(Whh, WB + 512, 512, 512, 512, 1024);
    prep_wf1<<<48, 512, 0, stream>>>(Wf1, Wf1p);
    prep_wf2<<<512, 64, 0, stream>>>(Wf2, Wf2p);
    hipMemsetAsync(hb0, 0, 2048ull * 512 * 2, stream);
    hipMemsetAsync(hf0, 0, 2048ull * 512 * 4, stream);

    // encoder (bf16 MFMA)
    gemm_bt<0><<<dim3(16, 16), 256, 0, stream>>>(xb, 4864, We1b, 4864, be1, h1b, 2048, 76, nullptr);
    gemm_bt<0><<<dim3(8, 16), 256, 0, stream>>>(h1b, 2048, We2b, 2048, be2, h2b, 1024, 32, nullptr);
    gemm_bt<0><<<dim3(4, 16), 256, 0, stream>>>(h2b, 1024, We3b, 1024, be3, h3b, 512, 16, nullptr);
    gemm_bt<1><<<dim3(4, 16), 256, 0, stream>>>(h3b, 512, We41b, 512, be41, encb, 512, 8, eps);

    // decoder: one fused kernel per step (linear grid, XCD-swizzled)
    gru_step<0><<<256, 1024, 0, stream>>>(encb, hb0, hf0, hb1, hf1, WB, bih,
                                          bhh, Wf1p, bf1, Wf2p, bf2, out, 0);
    for (int i = 1; i < 128; ++i) {
        int p = i & 1;
        gru_step<1><<<256, 1024, 0, stream>>>(nullptr, hb[p], hfl[p],
                                              hb[p ^ 1], hfl[p ^ 1], WB, bih,
                                              bhh, Wf1p, bf1, Wf2p, bf2, out,
                                              i - 1);
    }
    gru_step<2><<<32, 1024, 0, stream>>>(nullptr, hb0, hf0, nullptr, nullptr,
                                         WB, bih, bhh, Wf1p, bf1, Wf2p, bf2,
                                         out, 127);
}